// Round 5
// baseline (135.422 us; speedup 1.0000x reference)
//
#include <hip/hip_runtime.h>

// Where2comm AttenFusion, ego-row-only. R2 structure + bijective XCD-chunked
// block swizzle.
// x: (B=16, N=5, C=64, HW=25200) f32; out: (B, C, HW) f32.
// Per pixel p: dot[m] = <x[b,0,:,p], x[b,m,:,p]>/8; w = softmax(dot);
// out[b,:,p] = sum_m w[m]*x[b,m,:,p].
//
// Why the swizzle: plane stride 100800 B == 64 (mod 128). Odd-channel planes
// start mid-L2-line, so each block's 256B-per-plane read run straddles two
// half-used 128B boundary lines whose other halves belong to the ADJACENT
// block. Default dispatch round-robins consecutive blocks across the 8 XCDs
// (private L2s) -> every boundary line is HBM-fetched twice (~1.25x read
// amplification). Chunked swizzle puts logical neighbors (hw blocks i, i+8)
// on the SAME XCD so boundary lines hit in L2.

#define B_ 16
#define N_ 5
#define C_ 64
#define HW_ 25200
#define PG_PER_IMG (HW_ / 4)   // 6300 quads/image; 6300 blocks total
#define NBLK 6300
#define Q_ (NBLK / 8)          // 787
#define R_ (NBLK % 8)          // 4

typedef float f4 __attribute__((ext_vector_type(4)));

__global__ __launch_bounds__(256) void where2comm_atten_kernel(
    const float* __restrict__ x, float* __restrict__ out)
{
    // Bijective XCD-chunked swizzle (m204): hw block i dispatches to xcd i%8;
    // give each xcd a contiguous logical chunk.
    const int i    = blockIdx.x;
    const int xcd  = i & 7;
    const int slot = i >> 3;
    const int base = (xcd < R_) ? xcd * (Q_ + 1) : R_ * (Q_ + 1) + (xcd - R_) * Q_;
    const int lb   = base + slot;              // logical block id

    const int t   = threadIdx.x;
    const int l   = t & 63;
    const int pg  = lb * 16 + (t >> 6) * 4 + (l & 3);  // global 4-pixel group
    const int cl  = l >> 2;                            // chan-lane 0..15
    const int b   = pg / PG_PER_IMG;
    const int p   = (pg - b * PG_PER_IMG) * 4;         // pixel offset in image

    const float* xb = x + (size_t)b * (N_ * C_ * HW_) + (size_t)(cl * 4) * HW_ + p;

    // Load 5 cavs x 4 channels x 4 pixels, all dwordx4.
    f4 v[N_][4];
#pragma unroll
    for (int m = 0; m < N_; ++m)
#pragma unroll
        for (int j = 0; j < 4; ++j)
            v[m][j] = *reinterpret_cast<const f4*>(xb + (size_t)(m * C_ + j) * HW_);

    // Per-pixel partial dots over this lane's 4 channels.
    f4 d[N_];
#pragma unroll
    for (int m = 0; m < N_; ++m) {
        f4 acc = v[0][0] * v[m][0];
#pragma unroll
        for (int j = 1; j < 4; ++j) acc += v[0][j] * v[m][j];
        d[m] = acc;
    }

    // Reduce across the 16 chan-lanes (lane stride 4): masks 4,8,16,32.
#pragma unroll
    for (int mask = 4; mask <= 32; mask <<= 1)
#pragma unroll
        for (int m = 0; m < N_; ++m)
#pragma unroll
            for (int c = 0; c < 4; ++c)
                d[m][c] += __shfl_xor(d[m][c], mask);

    // Softmax over the 5 cavs, per pixel component.
    f4 wgt[N_];
#pragma unroll
    for (int c = 0; c < 4; ++c) {
        float dd[N_];
#pragma unroll
        for (int m = 0; m < N_; ++m) dd[m] = d[m][c] * 0.125f;  // / sqrt(64)
        float mx = dd[0];
#pragma unroll
        for (int m = 1; m < N_; ++m) mx = fmaxf(mx, dd[m]);
        float s = 0.f;
#pragma unroll
        for (int m = 0; m < N_; ++m) { dd[m] = __expf(dd[m] - mx); s += dd[m]; }
        const float inv = 1.0f / s;
#pragma unroll
        for (int m = 0; m < N_; ++m) wgt[m][c] = dd[m] * inv;
    }

    // out[b, cl*4+j, p..p+3] = sum_m wgt[m] * v[m][j]
    float* ob = out + (size_t)b * (C_ * HW_) + (size_t)(cl * 4) * HW_ + p;
#pragma unroll
    for (int j = 0; j < 4; ++j) {
        f4 a = wgt[0] * v[0][j];
#pragma unroll
        for (int m = 1; m < N_; ++m) a += wgt[m] * v[m][j];
        *reinterpret_cast<f4*>(ob + (size_t)j * HW_) = a;
    }
}

extern "C" void kernel_launch(void* const* d_in, const int* in_sizes, int n_in,
                              void* d_out, int out_size, void* d_ws, size_t ws_size,
                              hipStream_t stream) {
    const float* x = (const float*)d_in[0];
    float* out = (float*)d_out;
    where2comm_atten_kernel<<<NBLK, 256, 0, stream>>>(x, out);
}